// Round 1
// 525.688 us; speedup vs baseline: 1.3823x; 1.3823x over previous
//
#include <hip/hip_runtime.h>
#include <cstddef>

// ---------- helpers ----------
typedef __bf16 bf16x8 __attribute__((ext_vector_type(8)));
typedef float  floatx4 __attribute__((ext_vector_type(4)));

static __device__ __forceinline__ unsigned short f2bf(float f) {
    unsigned int u = __float_as_uint(f);
    u = u + 0x7fff + ((u >> 16) & 1);   // round-to-nearest-even
    return (unsigned short)(u >> 16);
}
static __device__ __forceinline__ float bflo(unsigned int u) {
    return __uint_as_float(u << 16);
}
static __device__ __forceinline__ float bfhi(unsigned int u) {
    return __uint_as_float(u & 0xffff0000u);
}

// ---------- kernel 1: W1 fp32 -> bf16 (proven, unchanged) ----------
__global__ __launch_bounds__(256) void nnue_convw1(
    const float* __restrict__ W1, unsigned short* __restrict__ W1b)
{
    const int i = (blockIdx.x * 256 + threadIdx.x) * 4;   // 128*4096 / 4 = 131072 threads
    const float4 v = *reinterpret_cast<const float4*>(W1 + i);
    ushort4 o;
    o.x = f2bf(v.x); o.y = f2bf(v.y); o.z = f2bf(v.z); o.w = f2bf(v.w);
    *reinterpret_cast<ushort4*>(W1b + i) = o;
}

// ---------- kernel 2: P = emb @ W1cat^T ----------
// P[f][n], f<40960, n<256:
//   n <  128: P[f][n] = sum_k emb[f][k]      * W1[n][k]        (k in [0,2048))
//   n >= 128: P[f][n] = sum_k emb[f][k]      * W1[n-128][2048+k]
// GEMM M=40960 N=256 K=2048, A fp32->bf16 on the fly, B already bf16.
// BM=64 (grid 640), BN=256 (full), BK=64, 512 threads = 8 waves (2m x 4n),
// wave tile 32x64. Fragment conventions copied verbatim from the proven
// round-1 MFMA kernel (A row = l16, B row(n) = l16, D: m=quad*4+r, n=l16).
#define LDST 72   // 64 + 8 bf16 pad (2-way bank alias only — free)
__global__ __launch_bounds__(512) void nnue_pgemm(
    const float* __restrict__ emb, const unsigned short* __restrict__ w1b,
    unsigned short* __restrict__ P)
{
    __shared__ unsigned short As[64 * LDST];    //  9.2 KB
    __shared__ unsigned short Bs[256 * LDST];   // 36.9 KB

    const int t    = threadIdx.x;
    const int wid  = t >> 6;
    const int lane = t & 63;
    const int quad = lane >> 4;
    const int l16  = lane & 15;
    const int wm   = wid >> 2;      // 0..1
    const int wn   = wid & 3;       // 0..3
    const int fbase = blockIdx.x * 64;

    floatx4 acc[2][4];
#pragma unroll
    for (int i = 0; i < 2; ++i)
#pragma unroll
        for (int j = 0; j < 4; ++j) acc[i][j] = (floatx4){0.f, 0.f, 0.f, 0.f};

    for (int kc = 0; kc < 2048; kc += 64) {
        __syncthreads();
        // stage A: 64 rows x 64 cols fp32 -> bf16 (1024 float4 chunks)
#pragma unroll
        for (int i = 0; i < 2; ++i) {
            const int c = t + i * 512;
            const int row = c >> 4, cc = c & 15;
            const float4 v = *reinterpret_cast<const float4*>(
                emb + (size_t)(fbase + row) * 2048 + kc + cc * 4);
            ushort4 o;
            o.x = f2bf(v.x); o.y = f2bf(v.y); o.z = f2bf(v.z); o.w = f2bf(v.w);
            *reinterpret_cast<ushort4*>(As + row * LDST + cc * 4) = o;
        }
        // stage B: 256 rows x 64 cols bf16 (2048 uint4 chunks)
#pragma unroll
        for (int i = 0; i < 4; ++i) {
            const int c = t + i * 512;
            const int row = c >> 3, cc = c & 7;
            const uint4 v = *reinterpret_cast<const uint4*>(
                w1b + (size_t)(row & 127) * 4096 + (row >> 7) * 2048 + kc + cc * 8);
            *reinterpret_cast<uint4*>(Bs + row * LDST + cc * 8) = v;
        }
        __syncthreads();
#pragma unroll
        for (int kk = 0; kk < 64; kk += 32) {
            const bf16x8 a0 = *reinterpret_cast<const bf16x8*>(
                As + (wm * 32 + l16) * LDST + kk + quad * 8);
            const bf16x8 a1 = *reinterpret_cast<const bf16x8*>(
                As + (wm * 32 + 16 + l16) * LDST + kk + quad * 8);
#pragma unroll
            for (int ni = 0; ni < 4; ++ni) {
                const bf16x8 bb = *reinterpret_cast<const bf16x8*>(
                    Bs + (wn * 64 + ni * 16 + l16) * LDST + kk + quad * 8);
                acc[0][ni] = __builtin_amdgcn_mfma_f32_16x16x32_bf16(a0, bb, acc[0][ni], 0, 0, 0);
                acc[1][ni] = __builtin_amdgcn_mfma_f32_16x16x32_bf16(a1, bb, acc[1][ni], 0, 0, 0);
            }
        }
    }

    // write P (bf16). D element: m = quad*4+r (within 16-block), n = l16.
#pragma unroll
    for (int mi = 0; mi < 2; ++mi) {
#pragma unroll
        for (int ni = 0; ni < 4; ++ni) {
            const int n = wn * 64 + ni * 16 + l16;
#pragma unroll
            for (int r = 0; r < 4; ++r) {
                const int f = fbase + wm * 32 + mi * 16 + quad * 4 + r;
                P[(size_t)f * 256 + n] = f2bf(acc[mi][ni][r]);
            }
        }
    }
}

// ---------- kernel 3: gather P rows + fused epilogue ----------
// out[b] = relu( sum_pieces P[idx][off..off+128] + b1 ) . W2 + b2
// 1 wave per batch element, 4 per block; lane owns 2 of the 128 h-columns.
// idx is wave-uniform per iteration; idx==0 rows are masked (branchless —
// the dead load hits the cached P[0] row).
__global__ __launch_bounds__(256) void nnue_out(
    const int* __restrict__ white, const int* __restrict__ black,
    const int* __restrict__ stm, const unsigned short* __restrict__ P,
    const float* __restrict__ b1, const float* __restrict__ W2,
    const float* __restrict__ b2, float* __restrict__ out)
{
    __shared__ int sW[128], sB[128];
    const int t = threadIdx.x;
    const int bbase = blockIdx.x * 4;
    if (t < 128) sW[t] = white[bbase * 32 + t];
    else         sB[t - 128] = black[bbase * 32 + (t - 128)];
    __syncthreads();

    const int w = t >> 6, lane = t & 63;
    const int b = bbase + w;
    // stm==1: x=[white,black] -> white uses Pa (cols 0..127), black Pb (128..255)
    const int offw = (stm[b] != 0) ? 0 : 128;
    const int offb = 128 - offw;
    const int n2 = lane * 2;

    float h0 = 0.f, h1 = 0.f;
#pragma unroll
    for (int i = 0; i < 32; ++i) {
        const int iw = sW[w * 32 + i];
        const unsigned int uw = *reinterpret_cast<const unsigned int*>(
            P + (size_t)iw * 256 + offw + n2);
        const float mw = (iw != 0) ? 1.f : 0.f;
        h0 += bflo(uw) * mw;
        h1 += bfhi(uw) * mw;

        const int ib = sB[w * 32 + i];
        const unsigned int ub = *reinterpret_cast<const unsigned int*>(
            P + (size_t)ib * 256 + offb + n2);
        const float mb = (ib != 0) ? 1.f : 0.f;
        h0 += bflo(ub) * mb;
        h1 += bfhi(ub) * mb;
    }

    h0 += b1[n2];     h1 += b1[n2 + 1];
    h0 = (h0 > 0.f) ? h0 : 0.f;
    h1 = (h1 > 0.f) ? h1 : 0.f;
    float s = h0 * W2[n2] + h1 * W2[n2 + 1];
#pragma unroll
    for (int m = 1; m < 64; m <<= 1) s += __shfl_xor(s, m, 64);
    if (lane == 0) out[b] = s + b2[0];
}

// ---------- launcher ----------
extern "C" void kernel_launch(void* const* d_in, const int* in_sizes, int n_in,
                              void* d_out, int out_size, void* d_ws, size_t ws_size,
                              hipStream_t stream)
{
    const int*   white = (const int*)d_in[0];
    const int*   black = (const int*)d_in[1];
    const int*   stm   = (const int*)d_in[2];
    const float* emb   = (const float*)d_in[3];
    const float* W1    = (const float*)d_in[4];
    const float* b1    = (const float*)d_in[5];
    const float* W2    = (const float*)d_in[6];
    const float* b2    = (const float*)d_in[7];
    float* out = (float*)d_out;

    unsigned short* w1buf = (unsigned short*)d_ws;                 // 128*4096 bf16 = 1 MiB
    unsigned short* pbuf  = w1buf + (size_t)128 * 4096;            // 40960*256 bf16 = 20 MiB

    nnue_convw1<<<512, 256, 0, stream>>>(W1, w1buf);
    nnue_pgemm<<<640, 512, 0, stream>>>(emb, w1buf, pbuf);
    nnue_out<<<1024, 256, 0, stream>>>(white, black, stm, pbuf, b1, W2, b2, out);
}

// Round 2
// 524.510 us; speedup vs baseline: 1.3854x; 1.0022x over previous
//
#include <hip/hip_runtime.h>
#include <cstddef>

// ---------- helpers ----------
typedef __bf16 bf16x8 __attribute__((ext_vector_type(8)));
typedef float  floatx4 __attribute__((ext_vector_type(4)));

static __device__ __forceinline__ unsigned short f2bf(float f) {
    unsigned int u = __float_as_uint(f);
    u = u + 0x7fff + ((u >> 16) & 1);   // round-to-nearest-even
    return (unsigned short)(u >> 16);
}
static __device__ __forceinline__ float bflo(unsigned int u) {
    return __uint_as_float(u << 16);
}
static __device__ __forceinline__ float bfhi(unsigned int u) {
    return __uint_as_float(u & 0xffff0000u);
}

// ---------- kernel 1: W1 fp32 -> bf16 (proven, unchanged) ----------
__global__ __launch_bounds__(256) void nnue_convw1(
    const float* __restrict__ W1, unsigned short* __restrict__ W1b)
{
    const int i = (blockIdx.x * 256 + threadIdx.x) * 4;   // 128*4096 / 4 = 131072 threads
    const float4 v = *reinterpret_cast<const float4*>(W1 + i);
    ushort4 o;
    o.x = f2bf(v.x); o.y = f2bf(v.y); o.z = f2bf(v.z); o.w = f2bf(v.w);
    *reinterpret_cast<ushort4*>(W1b + i) = o;
}

// ---------- kernel 2: P = emb @ W1cat^T ----------
// P[f][n], f<40960, n<256:
//   n <  128: P[f][n] = sum_k emb[f][k] * W1[n][k]
//   n >= 128: P[f][n] = sum_k emb[f][k] * W1[n-128][2048+k]
// GEMM M=40960 N=256 K=2048. BM=128, BN=128, BK=64; grid 320x2 = 640.
// 256 threads = 4 waves (2m x 2n), wave tile 64x64 -> 0.5 ds_reads/MFMA
// (m97-balanced). B: global_load_lds width-16 into linear [128][64] bf16
// with XOR swizzle (byte ^= (row&7)<<4) applied on BOTH the pre-swizzled
// global source address and the read address (rule #21). A: reg-staged
// fp32->bf16 into padded LDS (stride 72 shorts -> 2-way alias, free).
// Fragment conventions identical to the proven round-1 MFMA kernel.
#define ALDS 72   // 64 + 8 bf16 pad
__global__ __launch_bounds__(256) void nnue_pgemm(
    const float* __restrict__ emb, const unsigned short* __restrict__ w1b,
    unsigned short* __restrict__ P)
{
    __shared__ unsigned short As[128 * ALDS];   // 18.0 KB (padded)
    __shared__ unsigned short Bs[128 * 64];     // 16.0 KB (linear, swizzled contents)

    const int t    = threadIdx.x;
    const int wid  = t >> 6;
    const int lane = t & 63;
    const int quad = lane >> 4;
    const int l16  = lane & 15;
    const int wm   = wid >> 1;      // 0..1
    const int wn   = wid & 1;       // 0..1
    const int fbase = (blockIdx.x >> 1) * 128;
    const int nblk  = blockIdx.x & 1;

    // per-lane source-column swizzle for the B DMA (bytes).
    // chunk c covers rows r = c*8 + (lane>>3); within-row byte cb = (lane&7)*16.
    // LDS phys (r, cb) must hold global col (cb ^ ((r&7)<<4)); r&7 == lane>>3.
    const int bsrc_shorts = (((lane & 7) ^ (lane >> 3)) << 3);   // ((..)<<4)/2
    const int brow        = lane >> 3;

    floatx4 acc[4][4];
#pragma unroll
    for (int i = 0; i < 4; ++i)
#pragma unroll
        for (int j = 0; j < 4; ++j) acc[i][j] = (floatx4){0.f, 0.f, 0.f, 0.f};

    for (int kc = 0; kc < 2048; kc += 64) {
        __syncthreads();
        // --- B: 16 chunks x 1024 B direct-to-LDS (wave wid owns chunks wid*4..+3)
#pragma unroll
        for (int i = 0; i < 4; ++i) {
            const int c = wid * 4 + i;
            const int r = c * 8 + brow;                    // 0..127 (tile row)
            const unsigned short* g = w1b + (size_t)r * 4096 + nblk * 2048
                                    + kc + bsrc_shorts;
            auto* dst = (__attribute__((address_space(3))) unsigned int*)(Bs + c * 512);
            __builtin_amdgcn_global_load_lds(
                (const __attribute__((address_space(1))) unsigned int*)g,
                dst, 16, 0, 0);
        }
        // --- A: 128 rows x 64 cols fp32 -> bf16 (2048 float4 chunks, 8/thread)
#pragma unroll
        for (int i = 0; i < 8; ++i) {
            const int cch = t + i * 256;
            const int row = cch >> 4, cc = cch & 15;
            const float4 v = *reinterpret_cast<const float4*>(
                emb + (size_t)(fbase + row) * 2048 + kc + cc * 4);
            ushort4 o;
            o.x = f2bf(v.x); o.y = f2bf(v.y); o.z = f2bf(v.z); o.w = f2bf(v.w);
            *reinterpret_cast<ushort4*>(As + row * ALDS + cc * 4) = o;
        }
        __syncthreads();   // compiler drains vmcnt (DMA) + lgkm before barrier
        // --- compute: wave tile 64x64, 4a+4b frags -> 16 MFMA per kk
#pragma unroll
        for (int kk = 0; kk < 64; kk += 32) {
            bf16x8 a[4], b[4];
#pragma unroll
            for (int mi = 0; mi < 4; ++mi)
                a[mi] = *reinterpret_cast<const bf16x8*>(
                    As + (wm * 64 + mi * 16 + l16) * ALDS + kk + quad * 8);
#pragma unroll
            for (int ni = 0; ni < 4; ++ni) {
                const int r  = wn * 64 + ni * 16 + l16;          // r&7 == l16&7
                const int cb = (kk * 2 + quad * 16) ^ ((r & 7) << 4);
                b[ni] = *reinterpret_cast<const bf16x8*>(
                    reinterpret_cast<const char*>(Bs) + r * 128 + cb);
            }
#pragma unroll
            for (int mi = 0; mi < 4; ++mi)
#pragma unroll
                for (int ni = 0; ni < 4; ++ni)
                    acc[mi][ni] = __builtin_amdgcn_mfma_f32_16x16x32_bf16(
                        a[mi], b[ni], acc[mi][ni], 0, 0, 0);
        }
    }

    // write P (bf16). D element: m = quad*4+r (within 16-block), n = l16.
#pragma unroll
    for (int mi = 0; mi < 4; ++mi)
#pragma unroll
        for (int ni = 0; ni < 4; ++ni) {
            const int n = nblk * 128 + wn * 64 + ni * 16 + l16;
#pragma unroll
            for (int r = 0; r < 4; ++r) {
                const int f = fbase + wm * 64 + mi * 16 + quad * 4 + r;
                P[(size_t)f * 256 + n] = f2bf(acc[mi][ni][r]);
            }
        }
}

// ---------- kernel 3: gather P rows + fused epilogue (proven, unchanged) ----------
__global__ __launch_bounds__(256) void nnue_out(
    const int* __restrict__ white, const int* __restrict__ black,
    const int* __restrict__ stm, const unsigned short* __restrict__ P,
    const float* __restrict__ b1, const float* __restrict__ W2,
    const float* __restrict__ b2, float* __restrict__ out)
{
    __shared__ int sW[128], sB[128];
    const int t = threadIdx.x;
    const int bbase = blockIdx.x * 4;
    if (t < 128) sW[t] = white[bbase * 32 + t];
    else         sB[t - 128] = black[bbase * 32 + (t - 128)];
    __syncthreads();

    const int w = t >> 6, lane = t & 63;
    const int b = bbase + w;
    const int offw = (stm[b] != 0) ? 0 : 128;
    const int offb = 128 - offw;
    const int n2 = lane * 2;

    float h0 = 0.f, h1 = 0.f;
#pragma unroll
    for (int i = 0; i < 32; ++i) {
        const int iw = sW[w * 32 + i];
        const unsigned int uw = *reinterpret_cast<const unsigned int*>(
            P + (size_t)iw * 256 + offw + n2);
        const float mw = (iw != 0) ? 1.f : 0.f;
        h0 += bflo(uw) * mw;
        h1 += bfhi(uw) * mw;

        const int ib = sB[w * 32 + i];
        const unsigned int ub = *reinterpret_cast<const unsigned int*>(
            P + (size_t)ib * 256 + offb + n2);
        const float mb = (ib != 0) ? 1.f : 0.f;
        h0 += bflo(ub) * mb;
        h1 += bfhi(ub) * mb;
    }

    h0 += b1[n2];     h1 += b1[n2 + 1];
    h0 = (h0 > 0.f) ? h0 : 0.f;
    h1 = (h1 > 0.f) ? h1 : 0.f;
    float s = h0 * W2[n2] + h1 * W2[n2 + 1];
#pragma unroll
    for (int m = 1; m < 64; m <<= 1) s += __shfl_xor(s, m, 64);
    if (lane == 0) out[b] = s + b2[0];
}

// ---------- launcher ----------
extern "C" void kernel_launch(void* const* d_in, const int* in_sizes, int n_in,
                              void* d_out, int out_size, void* d_ws, size_t ws_size,
                              hipStream_t stream)
{
    const int*   white = (const int*)d_in[0];
    const int*   black = (const int*)d_in[1];
    const int*   stm   = (const int*)d_in[2];
    const float* emb   = (const float*)d_in[3];
    const float* W1    = (const float*)d_in[4];
    const float* b1    = (const float*)d_in[5];
    const float* W2    = (const float*)d_in[6];
    const float* b2    = (const float*)d_in[7];
    float* out = (float*)d_out;

    unsigned short* w1buf = (unsigned short*)d_ws;                 // 128*4096 bf16 = 1 MiB
    unsigned short* pbuf  = w1buf + (size_t)128 * 4096;            // 40960*256 bf16 = 20 MiB

    nnue_convw1<<<512, 256, 0, stream>>>(W1, w1buf);
    nnue_pgemm<<<640, 256, 0, stream>>>(emb, w1buf, pbuf);
    nnue_out<<<1024, 256, 0, stream>>>(white, black, stm, pbuf, b1, W2, b2, out);
}